// Round 5
// baseline (285.242 us; speedup 1.0000x reference)
//
#include <hip/hip_runtime.h>
#include <hip/hip_bf16.h>
#include <hip/hip_cooperative_groups.h>
#include <type_traits>

namespace cg = cooperative_groups;

// out = x @ M^T + c, with M = Wo @ Wv_sub (softmax row-sum == 1 collapses attn to v).
#define MROWS 4096   // B*S
#define EDIM  1024

typedef __attribute__((ext_vector_type(8))) __bf16 bf16x8;
typedef __attribute__((ext_vector_type(4))) float f32x4;
typedef __attribute__((ext_vector_type(8))) unsigned short ushort8;

__device__ __forceinline__ unsigned short f2bf(float f) {
    unsigned u = __builtin_bit_cast(unsigned, f);
    u += 0x7FFFu + ((u >> 16) & 1u);   // round-to-nearest-even
    return (unsigned short)(u >> 16);
}

__device__ __forceinline__ void async_load16(const void* g, void* l) {
    __builtin_amdgcn_global_load_lds(
        (const __attribute__((address_space(1))) void*)g,
        (__attribute__((address_space(3))) void*)l, 16, 0, 0);
}

// cast 8 consecutive f32 -> bf16 at flat ushort8 index i
__device__ __forceinline__ void cast8(const float* __restrict__ in,
                                      unsigned short* __restrict__ out, int i) {
    const float4* p = (const float4*)in + (size_t)i * 2;
    float4 a = p[0], b = p[1];
    ushort8 r;
    r[0] = f2bf(a.x); r[1] = f2bf(a.y); r[2] = f2bf(a.z); r[3] = f2bf(a.w);
    r[4] = f2bf(b.x); r[5] = f2bf(b.y); r[6] = f2bf(b.z); r[7] = f2bf(b.w);
    *((ushort8*)out + i) = r;
}

// ---------------- generic B^T-form bf16 MFMA GEMM body ----------------
// C[m,n] = sum_k A[m,k]*B[n,k] (+bias[n]). BMxBN tile, BK K-step, NWM x NWN
// waves. XCD-aware bijective swizzle: bm fastest within an XCD chunk so each
// XCD reuses a small B panel in its private L2. sm: >= (BM+BN)*BK ushorts.
template<bool BIAS, typename OUT_T, int MD, int ND, int KD,
         int BM, int BN, int BK, int NWM, int NWN>
__device__ __forceinline__ void gemm_bt_body(
    const unsigned short* __restrict__ A, const unsigned short* __restrict__ B,
    OUT_T* __restrict__ C, const float* __restrict__ bias, int id,
    unsigned short* sm)
{
    constexpr int THREADS = NWM * NWN * 64;
    constexpr int NBM = MD / BM, NBN = ND / BN, NWG = NBM * NBN;
    constexpr int CPX = NWG / 8;
    constexpr int WTM = BM / NWM, WTN = BN / NWN;
    constexpr int AM = WTM / 16, AN = WTN / 16;
    constexpr int CHUNKS = BK / 8;        // 16B chunks per LDS row
    constexpr int RPP = THREADS / CHUNKS; // staging rows per pass

    unsigned short* As = sm;
    unsigned short* Bs = sm + BM * BK;

    const int t = threadIdx.x;
    const int swz = (id & 7) * CPX + (id >> 3);
    const int bm = swz % NBM, bn = swz / NBM;

    const int lane = t & 63, wave = t >> 6;
    const int wr = wave / NWN, wc = wave % NWN;

    const int rsub = t / CHUNKS;          // 0..RPP-1
    const int kb   = (t % CHUNKS) * 8;    // bf16-elem offset within BK

    const unsigned short* Ag = A + (size_t)(bm * BM + rsub) * KD + kb;
    const unsigned short* Bg = B + (size_t)(bn * BN + rsub) * KD + kb;

    f32x4 acc[AM][AN] = {};

    for (int k0 = 0; k0 < KD; k0 += BK) {
        __syncthreads();
        #pragma unroll
        for (int p = 0; p < BM / RPP; ++p)
            async_load16(Ag + (size_t)(p * RPP) * KD + k0, &As[(rsub + p * RPP) * BK + kb]);
        #pragma unroll
        for (int p = 0; p < BN / RPP; ++p)
            async_load16(Bg + (size_t)(p * RPP) * KD + k0, &Bs[(rsub + p * RPP) * BK + kb]);
        __syncthreads();   // compiler emits vmcnt(0) drain before barrier

        #pragma unroll
        for (int ks = 0; ks < BK / 32; ++ks) {
            bf16x8 a[AM], b[AN];
            #pragma unroll
            for (int mi = 0; mi < AM; ++mi)
                a[mi] = *(const bf16x8*)&As[(wr * WTM + mi * 16 + (lane & 15)) * BK + ks * 32 + (lane >> 4) * 8];
            #pragma unroll
            for (int ni = 0; ni < AN; ++ni)
                b[ni] = *(const bf16x8*)&Bs[(wc * WTN + ni * 16 + (lane & 15)) * BK + ks * 32 + (lane >> 4) * 8];
            #pragma unroll
            for (int mi = 0; mi < AM; ++mi)
                #pragma unroll
                for (int ni = 0; ni < AN; ++ni)
                    acc[mi][ni] = __builtin_amdgcn_mfma_f32_16x16x32_bf16(
                        a[mi], b[ni], acc[mi][ni], 0, 0, 0);
        }
    }

    // C/D layout (m89/m91): col = lane&15, row = (lane>>4)*4 + reg.
    const int crow0 = bm * BM + wr * WTM + (lane >> 4) * 4;
    const int ccol0 = bn * BN + wc * WTN + (lane & 15);
    #pragma unroll
    for (int mi = 0; mi < AM; ++mi) {
        #pragma unroll
        for (int ni = 0; ni < AN; ++ni) {
            const int col = ccol0 + ni * 16;
            float bv = 0.f;
            if constexpr (BIAS) bv = bias[col];
            #pragma unroll
            for (int i = 0; i < 4; ++i) {
                const int row = crow0 + mi * 16 + i;
                float val = acc[mi][ni][i] + bv;
                if constexpr (std::is_same<OUT_T, float>::value)
                    C[(size_t)row * ND + col] = val;
                else
                    C[(size_t)row * ND + col] = f2bf(val);
            }
        }
    }
}

// ---------------- single cooperative kernel, 512 blocks x 256 threads ----------------
// Phase A (all): cast x; blocks 0-255 build WvT; blocks 256-511 cast Wo;
//                blocks 256-271 also compute cvec.
// Phase B (blocks 0-127): M = Wo @ Wv_sub, 64x128 tiles.
// Phase C (all): out = x @ M^T + c, 128x64 tiles (2 blocks/CU overlap).
__global__ __launch_bounds__(256, 4) void fused(
    const float* __restrict__ x, const float* __restrict__ Wqkv,
    const float* __restrict__ bqkv, const float* __restrict__ Wo,
    const float* __restrict__ bo,
    unsigned short* __restrict__ x_bf, unsigned short* __restrict__ wvt,
    unsigned short* __restrict__ wo_bf, unsigned short* __restrict__ m_bf,
    float* __restrict__ cvec, float* __restrict__ out)
{
    __shared__ unsigned short smem[12288];   // 24 KB, shared across phases
    const int blk = blockIdx.x;
    const int t = threadIdx.x;

    // ---------- Phase A ----------
    #pragma unroll
    for (int u = 0; u < 4; ++u)              // x -> bf16: 524288 ushort8 units
        cast8(x, x_bf, u * 131072 + blk * 256 + t);

    if (blk < 256) {                         // build WvT (one 64x64 tile)
        unsigned short (*tile)[65] = (unsigned short(*)[65])smem;
        const int eBase = (blk & 15) * 64, kBase = (blk >> 4) * 64;
        const int tx = t & 63, ty = t >> 6;
        #pragma unroll
        for (int r = ty; r < 64; r += 4) {
            int k = kBase + r;
            int j = ((k >> 6) * 192) + 128 + (k & 63);   // vrow(k)
            tile[r][tx] = f2bf(Wqkv[(size_t)j * EDIM + eBase + tx]);
        }
        __syncthreads();
        #pragma unroll
        for (int r = ty; r < 64; r += 4)
            wvt[(size_t)(eBase + r) * EDIM + kBase + tx] = tile[tx][r];
    } else {                                 // cast Wo: 131072 units over 256 blocks
        #pragma unroll
        for (int u = 0; u < 2; ++u)
            cast8(Wo, wo_bf, u * 65536 + (blk - 256) * 256 + t);
        if (blk < 272) {                     // fused bias c (16 blocks)
            const int b = blk - 256;
            const int wave = t >> 6, lane = t & 63;
            for (int r = 0; r < 16; ++r) {
                int row = b * 64 + wave * 16 + r;
                float s = 0.f;
                #pragma unroll
                for (int kk = 0; kk < 16; ++kk) {
                    int k = kk * 64 + lane;
                    int j = kk * 192 + 128 + lane;   // vrow(k)
                    s += Wo[(size_t)row * EDIM + k] * bqkv[j];
                }
                #pragma unroll
                for (int off = 32; off > 0; off >>= 1) s += __shfl_down(s, off);
                if (lane == 0) cvec[row] = s + bo[row];
            }
        }
    }

    __threadfence();
    cg::this_grid().sync();

    // ---------- Phase B ----------
    if (blk < 128)
        gemm_bt_body<false, unsigned short, EDIM, EDIM, EDIM, 64, 128, 64, 2, 2>(
            wo_bf, wvt, m_bf, nullptr, blk, smem);

    __threadfence();
    cg::this_grid().sync();

    // ---------- Phase C ----------
    gemm_bt_body<true, float, MROWS, EDIM, EDIM, 128, 64, 64, 2, 2>(
        x_bf, m_bf, out, cvec, blk, smem);
}

extern "C" void kernel_launch(void* const* d_in, const int* in_sizes, int n_in,
                              void* d_out, int out_size, void* d_ws, size_t ws_size,
                              hipStream_t stream) {
    const float* x    = (const float*)d_in[0];   // (2,2048,1024)
    const float* Wqkv = (const float*)d_in[1];   // (3072,1024)
    const float* bqkv = (const float*)d_in[2];   // (3072,)
    const float* Wo   = (const float*)d_in[3];   // (1024,1024)
    const float* bo   = (const float*)d_in[4];   // (1024,)
    float* out = (float*)d_out;                  // (2,2048,1024) f32

    char* ws = (char*)d_ws;
    unsigned short* x_bf  = (unsigned short*)(ws);                       // 8 MB
    unsigned short* wvt   = (unsigned short*)(ws + 8u  * 1024 * 1024);   // 2 MB
    unsigned short* wo_bf = (unsigned short*)(ws + 10u * 1024 * 1024);   // 2 MB
    unsigned short* m_bf  = (unsigned short*)(ws + 12u * 1024 * 1024);   // 2 MB
    float*          cvec  = (float*)(ws + 14u * 1024 * 1024);            // 4 KB

    void* args[] = {
        (void*)&x, (void*)&Wqkv, (void*)&bqkv, (void*)&Wo, (void*)&bo,
        (void*)&x_bf, (void*)&wvt, (void*)&wo_bf, (void*)&m_bf,
        (void*)&cvec, (void*)&out
    };
    hipLaunchCooperativeKernel((void*)fused, dim3(512), dim3(256), args, 0, stream);
}

// Round 6
// 47.470 us; speedup vs baseline: 6.0088x; 6.0088x over previous
//
#include <hip/hip_runtime.h>
#include <hip/hip_bf16.h>
#include <type_traits>

// out = x @ M^T + c, with M = Wo @ Wv_sub (softmax row-sum == 1 collapses attn to v).
#define MROWS 4096   // B*S
#define EDIM  1024

typedef __attribute__((ext_vector_type(8))) __bf16 bf16x8;
typedef __attribute__((ext_vector_type(4))) float f32x4;
typedef __attribute__((ext_vector_type(8))) unsigned short ushort8;

__device__ __forceinline__ unsigned short f2bf(float f) {
    unsigned u = __builtin_bit_cast(unsigned, f);
    u += 0x7FFFu + ((u >> 16) & 1u);   // round-to-nearest-even
    return (unsigned short)(u >> 16);
}

__device__ __forceinline__ void async_load16(const void* g, void* l) {
    __builtin_amdgcn_global_load_lds(
        (const __attribute__((address_space(1))) void*)g,
        (__attribute__((address_space(3))) void*)l, 16, 0, 0);
}

// cast 8 consecutive f32 -> bf16 at flat ushort8 index i
__device__ __forceinline__ void cast8(const float* __restrict__ in,
                                      unsigned short* __restrict__ out, int i) {
    const float4* p = (const float4*)in + (size_t)i * 2;
    float4 a = p[0], b = p[1];
    ushort8 r;
    r[0] = f2bf(a.x); r[1] = f2bf(a.y); r[2] = f2bf(a.z); r[3] = f2bf(a.w);
    r[4] = f2bf(b.x); r[5] = f2bf(b.y); r[6] = f2bf(b.z); r[7] = f2bf(b.w);
    *((ushort8*)out + i) = r;
}

// ---------------- 2-phase double-buffered B^T-form bf16 MFMA GEMM ----------------
// C[m,n] = sum_k A[m,k]*B[n,k] (+bias[n]). BMxBN tile, BK=64 K-step, NWM x NWN
// waves. T3-minimum pipeline: issue tile t+1's global_load_lds BEFORE computing
// tile t, so the compiler's pre-barrier vmcnt(0) drain overlaps the MFMA phase.
// XCD-aware bijective swizzle: bm fastest within an XCD chunk (B panel L2-reuse).
// sm must hold 2*(BM+BN)*BK ushorts.
template<bool BIAS, typename OUT_T, int MD, int ND, int KD,
         int BM, int BN, int BK, int NWM, int NWN>
__device__ __forceinline__ void gemm_bt_body(
    const unsigned short* __restrict__ A, const unsigned short* __restrict__ B,
    OUT_T* __restrict__ C, const float* __restrict__ bias, int id,
    unsigned short* sm)
{
    constexpr int THREADS = NWM * NWN * 64;
    constexpr int NBM = MD / BM, NBN = ND / BN, NWG = NBM * NBN;
    constexpr int CPX = NWG / 8;
    constexpr int WTM = BM / NWM, WTN = BN / NWN;
    constexpr int AM = WTM / 16, AN = WTN / 16;
    constexpr int CHUNKS = BK / 8;        // 16B chunks per LDS row
    constexpr int RPP = THREADS / CHUNKS; // staging rows per pass
    constexpr int TILE = (BM + BN) * BK;  // ushorts per buffer

    const int t = threadIdx.x;
    const int swz = (id & 7) * CPX + (id >> 3);
    const int bm = swz % NBM, bn = swz / NBM;

    const int lane = t & 63, wave = t >> 6;
    const int wr = wave / NWN, wc = wave % NWN;

    const int rsub = t / CHUNKS;          // 0..RPP-1
    const int kb   = (t % CHUNKS) * 8;    // bf16-elem offset within BK

    const unsigned short* Ag = A + (size_t)(bm * BM + rsub) * KD + kb;
    const unsigned short* Bg = B + (size_t)(bn * BN + rsub) * KD + kb;

    f32x4 acc[AM][AN] = {};

    auto stage = [&](int buf, int k0) {
        unsigned short* As = sm + buf * TILE;
        unsigned short* Bs = As + BM * BK;
        #pragma unroll
        for (int p = 0; p < BM / RPP; ++p)
            async_load16(Ag + (size_t)(p * RPP) * KD + k0, &As[(rsub + p * RPP) * BK + kb]);
        #pragma unroll
        for (int p = 0; p < BN / RPP; ++p)
            async_load16(Bg + (size_t)(p * RPP) * KD + k0, &Bs[(rsub + p * RPP) * BK + kb]);
    };

    auto compute = [&](int buf) {
        const unsigned short* As = sm + buf * TILE;
        const unsigned short* Bs = As + BM * BK;
        #pragma unroll
        for (int ks = 0; ks < BK / 32; ++ks) {
            bf16x8 a[AM], b[AN];
            #pragma unroll
            for (int mi = 0; mi < AM; ++mi)
                a[mi] = *(const bf16x8*)&As[(wr * WTM + mi * 16 + (lane & 15)) * BK + ks * 32 + (lane >> 4) * 8];
            #pragma unroll
            for (int ni = 0; ni < AN; ++ni)
                b[ni] = *(const bf16x8*)&Bs[(wc * WTN + ni * 16 + (lane & 15)) * BK + ks * 32 + (lane >> 4) * 8];
            #pragma unroll
            for (int mi = 0; mi < AM; ++mi)
                #pragma unroll
                for (int ni = 0; ni < AN; ++ni)
                    acc[mi][ni] = __builtin_amdgcn_mfma_f32_16x16x32_bf16(
                        a[mi], b[ni], acc[mi][ni], 0, 0, 0);
        }
    };

    // prologue: tile 0 staged and drained
    stage(0, 0);
    __syncthreads();
    int cur = 0;
    for (int k0 = BK; k0 < KD; k0 += BK) {
        stage(cur ^ 1, k0);   // next tile's loads fly during this tile's MFMAs
        compute(cur);
        __syncthreads();      // vmcnt(0) drain lands after compute, mostly hidden
        cur ^= 1;
    }
    compute(cur);

    // C/D layout (m89/m91): col = lane&15, row = (lane>>4)*4 + reg.
    const int crow0 = bm * BM + wr * WTM + (lane >> 4) * 4;
    const int ccol0 = bn * BN + wc * WTN + (lane & 15);
    #pragma unroll
    for (int mi = 0; mi < AM; ++mi) {
        #pragma unroll
        for (int ni = 0; ni < AN; ++ni) {
            const int col = ccol0 + ni * 16;
            float bv = 0.f;
            if constexpr (BIAS) bv = bias[col];
            #pragma unroll
            for (int i = 0; i < 4; ++i) {
                const int row = crow0 + mi * 16 + i;
                float val = acc[mi][ni][i] + bv;
                if constexpr (std::is_same<OUT_T, float>::value)
                    C[(size_t)row * ND + col] = val;
                else
                    C[(size_t)row * ND + col] = f2bf(val);
            }
        }
    }
}

// ---------------- K1: weight prep ----------------
// blocks [0,256):   WvT[e,k] = bf16(Wqkv[vrow(k), e])  (16x16 tiles of 64x64)
// blocks [256,768): Wo -> bf16
// blocks [768,784): c[i] = bo[i] + sum_k Wo[i,k]*bqkv[vrow(k)]
__global__ __launch_bounds__(256) void prep_w(
    const float* __restrict__ Wqkv, const float* __restrict__ bqkv,
    const float* __restrict__ Wo, const float* __restrict__ bo,
    unsigned short* __restrict__ WvT, unsigned short* __restrict__ wo_bf,
    float* __restrict__ c)
{
    const int blk = blockIdx.x;
    const int t = threadIdx.x;
    if (blk < 256) {                        // ---- build WvT ----
        __shared__ unsigned short tile[64][65];
        const int eBase = (blk & 15) * 64, kBase = (blk >> 4) * 64;
        const int tx = t & 63, ty = t >> 6;
        #pragma unroll
        for (int r = ty; r < 64; r += 4) {
            int k = kBase + r;
            int j = ((k >> 6) * 192) + 128 + (k & 63);   // vrow(k)
            tile[r][tx] = f2bf(Wqkv[(size_t)j * EDIM + eBase + tx]);
        }
        __syncthreads();
        #pragma unroll
        for (int r = ty; r < 64; r += 4)
            WvT[(size_t)(eBase + r) * EDIM + kBase + tx] = tile[tx][r];
    } else if (blk < 768) {                 // ---- cast Wo ----
        cast8(Wo, wo_bf, (blk - 256) * 256 + t);
    } else {                                // ---- fused bias c ----
        const int b = blk - 768;            // 0..15
        const int wave = t >> 6, lane = t & 63;
        for (int r = 0; r < 16; ++r) {
            int row = b * 64 + wave * 16 + r;
            float s = 0.f;
            #pragma unroll
            for (int kk = 0; kk < 16; ++kk) {
                int k = kk * 64 + lane;
                int j = kk * 192 + 128 + lane;   // vrow(k)
                s += Wo[(size_t)row * EDIM + k] * bqkv[j];
            }
            #pragma unroll
            for (int off = 32; off > 0; off >>= 1) s += __shfl_down(s, off);
            if (lane == 0) c[row] = s + bo[row];
        }
    }
}

// ---------------- K2: gemm1 (M = Wo @ Wv_sub) co-dispatched with cast_x ----------------
// blocks [0,256):    M GEMM, 64x64 tiles (one block per CU), 2-phase, 32KB LDS
// blocks [256,2304): x -> bf16 (4M elems, 2048 elems/block)
__global__ __launch_bounds__(256, 2) void gemm1_castx(
    const unsigned short* __restrict__ wo_bf, const unsigned short* __restrict__ wvt,
    unsigned short* __restrict__ m_bf,
    const float* __restrict__ x, unsigned short* __restrict__ x_bf)
{
    __shared__ unsigned short smem[2 * (64 + 64) * 64];   // 32 KB
    const int blk = blockIdx.x;
    if (blk < 256) {
        gemm_bt_body<false, unsigned short, EDIM, EDIM, EDIM, 64, 64, 64, 2, 2>(
            wo_bf, wvt, m_bf, nullptr, blk, smem);
    } else {
        cast8(x, x_bf, (blk - 256) * 256 + threadIdx.x);
    }
}

// ---------------- K3: out = x @ M^T + c ----------------
// 128x64 tiles, BK=64, 2-phase double-buffer, 48KB LDS,
// 512 blocks = 2 blocks/CU co-residency.
__global__ __launch_bounds__(256, 2) void gemm2(
    const unsigned short* __restrict__ x_bf, const unsigned short* __restrict__ m_bf,
    float* __restrict__ out, const float* __restrict__ cvec)
{
    __shared__ unsigned short smem[2 * (128 + 64) * 64];  // 48 KB
    gemm_bt_body<true, float, MROWS, EDIM, EDIM, 128, 64, 64, 2, 2>(
        x_bf, m_bf, out, cvec, blockIdx.x, smem);
}

extern "C" void kernel_launch(void* const* d_in, const int* in_sizes, int n_in,
                              void* d_out, int out_size, void* d_ws, size_t ws_size,
                              hipStream_t stream) {
    const float* x    = (const float*)d_in[0];   // (2,2048,1024)
    const float* Wqkv = (const float*)d_in[1];   // (3072,1024)
    const float* bqkv = (const float*)d_in[2];   // (3072,)
    const float* Wo   = (const float*)d_in[3];   // (1024,1024)
    const float* bo   = (const float*)d_in[4];   // (1024,)
    float* out = (float*)d_out;                  // (2,2048,1024) f32

    char* ws = (char*)d_ws;
    unsigned short* x_bf  = (unsigned short*)(ws);                       // 8 MB
    unsigned short* wvt   = (unsigned short*)(ws + 8u  * 1024 * 1024);   // 2 MB
    unsigned short* wo_bf = (unsigned short*)(ws + 10u * 1024 * 1024);   // 2 MB
    unsigned short* m_bf  = (unsigned short*)(ws + 12u * 1024 * 1024);   // 2 MB
    float*          cvec  = (float*)(ws + 14u * 1024 * 1024);            // 4 KB

    // K1: weight prep (WvT gather/transpose, Wo cast, fused bias c)
    prep_w<<<784, 256, 0, stream>>>(Wqkv, bqkv, Wo, bo, wvt, wo_bf, cvec);
    // K2: M = Wo @ Wv_sub (256 blocks, 2-phase)  ||  x -> bf16 (2048 blocks)
    gemm1_castx<<<2304, 256, 0, stream>>>(wo_bf, wvt, m_bf, x, x_bf);
    // K3: out = x @ M^T + c (2-phase double-buffer)
    gemm2<<<512, 256, 0, stream>>>(x_bf, m_bf, out, cvec);
}

// Round 7
// 46.411 us; speedup vs baseline: 6.1460x; 1.0228x over previous
//
#include <hip/hip_runtime.h>
#include <hip/hip_bf16.h>
#include <type_traits>

// out = x @ M^T + c, with M = Wo @ Wv_sub (softmax row-sum == 1 collapses attn to v).
#define MROWS 4096   // B*S
#define EDIM  1024

typedef __attribute__((ext_vector_type(8))) __bf16 bf16x8;
typedef __attribute__((ext_vector_type(4))) float f32x4;
typedef __attribute__((ext_vector_type(8))) unsigned short ushort8;

__device__ __forceinline__ unsigned short f2bf(float f) {
    unsigned u = __builtin_bit_cast(unsigned, f);
    u += 0x7FFFu + ((u >> 16) & 1u);   // round-to-nearest-even
    return (unsigned short)(u >> 16);
}

__device__ __forceinline__ void async_load16(const void* g, void* l) {
    __builtin_amdgcn_global_load_lds(
        (const __attribute__((address_space(1))) void*)g,
        (__attribute__((address_space(3))) void*)l, 16, 0, 0);
}

template<int N> __device__ __forceinline__ void wait_vmcnt() {
    if constexpr (N == 0)       asm volatile("s_waitcnt vmcnt(0)" ::: "memory");
    else if constexpr (N == 4)  asm volatile("s_waitcnt vmcnt(4)" ::: "memory");
    else if constexpr (N == 6)  asm volatile("s_waitcnt vmcnt(6)" ::: "memory");
    else if constexpr (N == 8)  asm volatile("s_waitcnt vmcnt(8)" ::: "memory");
    else if constexpr (N == 12) asm volatile("s_waitcnt vmcnt(12)" ::: "memory");
    else static_assert(N < 0, "unsupported vmcnt literal");
}

// cast 8 consecutive f32 -> bf16 at flat ushort8 index i
__device__ __forceinline__ void cast8(const float* __restrict__ in,
                                      unsigned short* __restrict__ out, int i) {
    const float4* p = (const float4*)in + (size_t)i * 2;
    float4 a = p[0], b = p[1];
    ushort8 r;
    r[0] = f2bf(a.x); r[1] = f2bf(a.y); r[2] = f2bf(a.z); r[3] = f2bf(a.w);
    r[4] = f2bf(b.x); r[5] = f2bf(b.y); r[6] = f2bf(b.z); r[7] = f2bf(b.w);
    *((ushort8*)out + i) = r;
}

// ---------------- 3-buffer counted-vmcnt B^T-form bf16 MFMA GEMM (T3+T4) ------
// C[m,n] = sum_k A[m,k]*B[n,k] (+bias[n]). BMxBN tile, BK=64, NWM x NWN waves.
// Pipeline: 2 tiles in flight; raw s_barrier + s_waitcnt vmcnt(2L) (never 0 in
// steady state). Stage of buf[(t+2)%3] is issued only after the barrier that
// proves compute(t-1) (the last reader of that buffer) retired -> race-free.
// Each wave waits for ITS OWN tile-t loads (vmcnt<=2L) before the second
// barrier, so barrier-arrival implies tile t is fully in LDS for all waves.
// XCD-aware bijective swizzle: bm fastest within an XCD chunk (B panel L2-reuse).
// sm must hold 3*(BM+BN)*BK ushorts.
template<bool BIAS, typename OUT_T, int MD, int ND, int KD,
         int BM, int BN, int BK, int NWM, int NWN>
__device__ __forceinline__ void gemm_bt_body(
    const unsigned short* __restrict__ A, const unsigned short* __restrict__ B,
    OUT_T* __restrict__ C, const float* __restrict__ bias, int id,
    unsigned short* sm)
{
    constexpr int THREADS = NWM * NWN * 64;
    constexpr int NBM = MD / BM, NBN = ND / BN, NWG = NBM * NBN;
    constexpr int CPX = NWG / 8;
    constexpr int WTM = BM / NWM, WTN = BN / NWN;
    constexpr int AM = WTM / 16, AN = WTN / 16;
    constexpr int CHUNKS = BK / 8;        // 16B chunks per LDS row
    constexpr int RPP = THREADS / CHUNKS; // staging rows per pass
    constexpr int TILE = (BM + BN) * BK;  // ushorts per buffer
    constexpr int L = BM / RPP + BN / RPP;   // async loads per thread per stage
    constexpr int NIT = KD / BK;

    const int t = threadIdx.x;
    const int swz = (id & 7) * CPX + (id >> 3);
    const int bm = swz % NBM, bn = swz / NBM;

    const int lane = t & 63, wave = t >> 6;
    const int wr = wave / NWN, wc = wave % NWN;

    const int rsub = t / CHUNKS;          // 0..RPP-1
    const int kb   = (t % CHUNKS) * 8;    // bf16-elem offset within BK

    const unsigned short* Ag = A + (size_t)(bm * BM + rsub) * KD + kb;
    const unsigned short* Bg = B + (size_t)(bn * BN + rsub) * KD + kb;

    f32x4 acc[AM][AN] = {};

    auto stage = [&](int buf, int k0) {
        unsigned short* As = sm + buf * TILE;
        unsigned short* Bs = As + BM * BK;
        #pragma unroll
        for (int p = 0; p < BM / RPP; ++p)
            async_load16(Ag + (size_t)(p * RPP) * KD + k0, &As[(rsub + p * RPP) * BK + kb]);
        #pragma unroll
        for (int p = 0; p < BN / RPP; ++p)
            async_load16(Bg + (size_t)(p * RPP) * KD + k0, &Bs[(rsub + p * RPP) * BK + kb]);
    };

    auto compute = [&](int buf) {
        const unsigned short* As = sm + buf * TILE;
        const unsigned short* Bs = As + BM * BK;
        #pragma unroll
        for (int ks = 0; ks < BK / 32; ++ks) {
            bf16x8 a[AM], b[AN];
            #pragma unroll
            for (int mi = 0; mi < AM; ++mi)
                a[mi] = *(const bf16x8*)&As[(wr * WTM + mi * 16 + (lane & 15)) * BK + ks * 32 + (lane >> 4) * 8];
            #pragma unroll
            for (int ni = 0; ni < AN; ++ni)
                b[ni] = *(const bf16x8*)&Bs[(wc * WTN + ni * 16 + (lane & 15)) * BK + ks * 32 + (lane >> 4) * 8];
            #pragma unroll
            for (int mi = 0; mi < AM; ++mi)
                #pragma unroll
                for (int ni = 0; ni < AN; ++ni)
                    acc[mi][ni] = __builtin_amdgcn_mfma_f32_16x16x32_bf16(
                        a[mi], b[ni], acc[mi][ni], 0, 0, 0);
        }
    };

    // prologue: 2 tiles in flight
    stage(0, 0);
    stage(1, BK);

    for (int it = 0; it < NIT; ++it) {
        __builtin_amdgcn_s_barrier();            // all waves retired compute(it-1)
        if (it + 2 < NIT) {
            stage((it + 2) % 3, (it + 2) * BK);  // overwrite target retired 1 iter ago
            wait_vmcnt<2 * L>();                 // my tile-it loads have landed
        } else if (it + 1 < NIT) {
            wait_vmcnt<L>();
        } else {
            wait_vmcnt<0>();
        }
        __builtin_amdgcn_s_barrier();            // everyone's tile-it in LDS
        compute(it % 3);
    }

    // C/D layout (m89/m91): col = lane&15, row = (lane>>4)*4 + reg.
    const int crow0 = bm * BM + wr * WTM + (lane >> 4) * 4;
    const int ccol0 = bn * BN + wc * WTN + (lane & 15);
    #pragma unroll
    for (int mi = 0; mi < AM; ++mi) {
        #pragma unroll
        for (int ni = 0; ni < AN; ++ni) {
            const int col = ccol0 + ni * 16;
            float bv = 0.f;
            if constexpr (BIAS) bv = bias[col];
            #pragma unroll
            for (int i = 0; i < 4; ++i) {
                const int row = crow0 + mi * 16 + i;
                float val = acc[mi][ni][i] + bv;
                if constexpr (std::is_same<OUT_T, float>::value)
                    C[(size_t)row * ND + col] = val;
                else
                    C[(size_t)row * ND + col] = f2bf(val);
            }
        }
    }
}

// ---------------- K1: weight prep ----------------
// blocks [0,256):   WvT[e,k] = bf16(Wqkv[vrow(k), e])  (16x16 tiles of 64x64)
// blocks [256,768): Wo -> bf16
// blocks [768,784): c[i] = bo[i] + sum_k Wo[i,k]*bqkv[vrow(k)]
__global__ __launch_bounds__(256) void prep_w(
    const float* __restrict__ Wqkv, const float* __restrict__ bqkv,
    const float* __restrict__ Wo, const float* __restrict__ bo,
    unsigned short* __restrict__ WvT, unsigned short* __restrict__ wo_bf,
    float* __restrict__ c)
{
    const int blk = blockIdx.x;
    const int t = threadIdx.x;
    if (blk < 256) {                        // ---- build WvT ----
        __shared__ unsigned short tile[64][65];
        const int eBase = (blk & 15) * 64, kBase = (blk >> 4) * 64;
        const int tx = t & 63, ty = t >> 6;
        #pragma unroll
        for (int r = ty; r < 64; r += 4) {
            int k = kBase + r;
            int j = ((k >> 6) * 192) + 128 + (k & 63);   // vrow(k)
            tile[r][tx] = f2bf(Wqkv[(size_t)j * EDIM + eBase + tx]);
        }
        __syncthreads();
        #pragma unroll
        for (int r = ty; r < 64; r += 4)
            WvT[(size_t)(eBase + r) * EDIM + kBase + tx] = tile[tx][r];
    } else if (blk < 768) {                 // ---- cast Wo ----
        cast8(Wo, wo_bf, (blk - 256) * 256 + t);
    } else {                                // ---- fused bias c ----
        const int b = blk - 768;            // 0..15
        const int wave = t >> 6, lane = t & 63;
        for (int r = 0; r < 16; ++r) {
            int row = b * 64 + wave * 16 + r;
            float s = 0.f;
            #pragma unroll
            for (int kk = 0; kk < 16; ++kk) {
                int k = kk * 64 + lane;
                int j = kk * 192 + 128 + lane;   // vrow(k)
                s += Wo[(size_t)row * EDIM + k] * bqkv[j];
            }
            #pragma unroll
            for (int off = 32; off > 0; off >>= 1) s += __shfl_down(s, off);
            if (lane == 0) c[row] = s + bo[row];
        }
    }
}

// ---------------- K2: gemm1 (M = Wo @ Wv_sub) co-dispatched with cast_x ----------------
// blocks [0,256):    M GEMM, 64x64 tiles (one block per CU), 3-buf counted-vmcnt
// blocks [256,2304): x -> bf16 (4M elems, 2048 elems/block)
__global__ __launch_bounds__(256, 2) void gemm1_castx(
    const unsigned short* __restrict__ wo_bf, const unsigned short* __restrict__ wvt,
    unsigned short* __restrict__ m_bf,
    const float* __restrict__ x, unsigned short* __restrict__ x_bf)
{
    __shared__ unsigned short smem[3 * (64 + 64) * 64];   // 48 KB
    const int blk = blockIdx.x;
    if (blk < 256) {
        gemm_bt_body<false, unsigned short, EDIM, EDIM, EDIM, 64, 64, 64, 2, 2>(
            wo_bf, wvt, m_bf, nullptr, blk, smem);
    } else {
        cast8(x, x_bf, (blk - 256) * 256 + threadIdx.x);
    }
}

// ---------------- K3: out = x @ M^T + c ----------------
// 128x64 tiles, BK=64, 3-buffer counted-vmcnt (vmcnt(12) steady state),
// 72 KB LDS -> 2 blocks/CU co-residency.
__global__ __launch_bounds__(256, 2) void gemm2(
    const unsigned short* __restrict__ x_bf, const unsigned short* __restrict__ m_bf,
    float* __restrict__ out, const float* __restrict__ cvec)
{
    __shared__ unsigned short smem[3 * (128 + 64) * 64];  // 72 KB
    gemm_bt_body<true, float, MROWS, EDIM, EDIM, 128, 64, 64, 2, 2>(
        x_bf, m_bf, out, cvec, blockIdx.x, smem);
}

extern "C" void kernel_launch(void* const* d_in, const int* in_sizes, int n_in,
                              void* d_out, int out_size, void* d_ws, size_t ws_size,
                              hipStream_t stream) {
    const float* x    = (const float*)d_in[0];   // (2,2048,1024)
    const float* Wqkv = (const float*)d_in[1];   // (3072,1024)
    const float* bqkv = (const float*)d_in[2];   // (3072,)
    const float* Wo   = (const float*)d_in[3];   // (1024,1024)
    const float* bo   = (const float*)d_in[4];   // (1024,)
    float* out = (float*)d_out;                  // (2,2048,1024) f32

    char* ws = (char*)d_ws;
    unsigned short* x_bf  = (unsigned short*)(ws);                       // 8 MB
    unsigned short* wvt   = (unsigned short*)(ws + 8u  * 1024 * 1024);   // 2 MB
    unsigned short* wo_bf = (unsigned short*)(ws + 10u * 1024 * 1024);   // 2 MB
    unsigned short* m_bf  = (unsigned short*)(ws + 12u * 1024 * 1024);   // 2 MB
    float*          cvec  = (float*)(ws + 14u * 1024 * 1024);            // 4 KB

    // K1: weight prep (WvT gather/transpose, Wo cast, fused bias c)
    prep_w<<<784, 256, 0, stream>>>(Wqkv, bqkv, Wo, bo, wvt, wo_bf, cvec);
    // K2: M = Wo @ Wv_sub (256 blocks, counted-vmcnt)  ||  x -> bf16 (2048 blocks)
    gemm1_castx<<<2304, 256, 0, stream>>>(wo_bf, wvt, m_bf, x, x_bf);
    // K3: out = x @ M^T + c (3-buffer counted-vmcnt pipeline)
    gemm2<<<512, 256, 0, stream>>>(x_bf, m_bf, out, cvec);
}

// Round 8
// 43.992 us; speedup vs baseline: 6.4839x; 1.0550x over previous
//
#include <hip/hip_runtime.h>
#include <hip/hip_bf16.h>
#include <type_traits>

// out = x @ M^T + c, with M = Wo @ Wv_sub (softmax row-sum == 1 collapses attn to v).
#define MROWS 4096   // B*S
#define EDIM  1024

typedef __attribute__((ext_vector_type(8))) __bf16 bf16x8;
typedef __attribute__((ext_vector_type(4))) float f32x4;
typedef __attribute__((ext_vector_type(8))) unsigned short ushort8;

__device__ __forceinline__ unsigned short f2bf(float f) {
    unsigned u = __builtin_bit_cast(unsigned, f);
    u += 0x7FFFu + ((u >> 16) & 1u);   // round-to-nearest-even
    return (unsigned short)(u >> 16);
}

__device__ __forceinline__ void async_load16(const void* g, void* l) {
    __builtin_amdgcn_global_load_lds(
        (const __attribute__((address_space(1))) void*)g,
        (__attribute__((address_space(3))) void*)l, 16, 0, 0);
}

template<int N> __device__ __forceinline__ void wait_vmcnt() {
    if constexpr (N == 0)       asm volatile("s_waitcnt vmcnt(0)" ::: "memory");
    else if constexpr (N == 4)  asm volatile("s_waitcnt vmcnt(4)" ::: "memory");
    else if constexpr (N == 6)  asm volatile("s_waitcnt vmcnt(6)" ::: "memory");
    else if constexpr (N == 8)  asm volatile("s_waitcnt vmcnt(8)" ::: "memory");
    else if constexpr (N == 12) asm volatile("s_waitcnt vmcnt(12)" ::: "memory");
    else static_assert(N < 0, "unsupported vmcnt literal");
}

// cast 8 consecutive f32 -> bf16 at flat ushort8 index i
__device__ __forceinline__ void cast8(const float* __restrict__ in,
                                      unsigned short* __restrict__ out, int i) {
    const float4* p = (const float4*)in + (size_t)i * 2;
    float4 a = p[0], b = p[1];
    ushort8 r;
    r[0] = f2bf(a.x); r[1] = f2bf(a.y); r[2] = f2bf(a.z); r[3] = f2bf(a.w);
    r[4] = f2bf(b.x); r[5] = f2bf(b.y); r[6] = f2bf(b.z); r[7] = f2bf(b.w);
    *((ushort8*)out + i) = r;
}

// ---------------- 3-buffer counted-vmcnt + T2-swizzled bf16 MFMA GEMM ----------
// C[m,n] = sum_k A[m,k]*B[n,k] (+bias[n]). BMxBN tile, BK=64, NWM x NWN waves.
// T3+T4: 2 tiles in flight, raw s_barrier, counted vmcnt (never 0 steady-state).
// T2 (rule #21): global_load_lds writes LDS LINEARLY, so the bank-conflict
// swizzle is applied as inverse-permuted GLOBAL SOURCE (kb ^ (row&7)*8, a 16B-
// chunk XOR within the 128B row) + the SAME XOR on the ds_read address. This
// spreads the 16 fragment rows over all 32 banks (2 lanes/bank = free, m136)
// instead of a 16-way conflict on every ds_read_b128.
// XCD-aware bijective swizzle: bm fastest within an XCD chunk (B panel L2-reuse).
// sm must hold 3*(BM+BN)*BK ushorts.
template<bool BIAS, typename OUT_T, int MD, int ND, int KD,
         int BM, int BN, int BK, int NWM, int NWN>
__device__ __forceinline__ void gemm_bt_body(
    const unsigned short* __restrict__ A, const unsigned short* __restrict__ B,
    OUT_T* __restrict__ C, const float* __restrict__ bias, int id,
    unsigned short* sm)
{
    constexpr int THREADS = NWM * NWN * 64;
    constexpr int NBM = MD / BM, NBN = ND / BN, NWG = NBM * NBN;
    constexpr int CPX = NWG / 8;
    constexpr int WTM = BM / NWM, WTN = BN / NWN;
    constexpr int AM = WTM / 16, AN = WTN / 16;
    constexpr int CHUNKS = BK / 8;        // 16B chunks per LDS row
    constexpr int RPP = THREADS / CHUNKS; // staging rows per pass
    constexpr int TILE = (BM + BN) * BK;  // ushorts per buffer
    constexpr int L = BM / RPP + BN / RPP;   // async loads per thread per stage
    constexpr int NIT = KD / BK;
    static_assert(RPP % 8 == 0, "row-phase must be p-invariant for source swizzle");
    static_assert(CHUNKS == 8, "XOR swizzle assumes 8 chunks per row");

    const int t = threadIdx.x;
    const int swz = (id & 7) * CPX + (id >> 3);
    const int bm = swz % NBM, bn = swz / NBM;

    const int lane = t & 63, wave = t >> 6;
    const int wr = wave / NWN, wc = wave % NWN;

    const int rsub = t / CHUNKS;          // 0..RPP-1
    const int kb   = (t % CHUNKS) * 8;    // bf16-elem offset within BK (LDS dest)
    const int kbs  = kb ^ ((rsub & 7) * 8);  // inverse-swizzled global source

    const unsigned short* Ag = A + (size_t)(bm * BM + rsub) * KD + kbs;
    const unsigned short* Bg = B + (size_t)(bn * BN + rsub) * KD + kbs;

    f32x4 acc[AM][AN] = {};

    auto stage = [&](int buf, int k0) {
        unsigned short* As = sm + buf * TILE;
        unsigned short* Bs = As + BM * BK;
        #pragma unroll
        for (int p = 0; p < BM / RPP; ++p)
            async_load16(Ag + (size_t)(p * RPP) * KD + k0, &As[(rsub + p * RPP) * BK + kb]);
        #pragma unroll
        for (int p = 0; p < BN / RPP; ++p)
            async_load16(Bg + (size_t)(p * RPP) * KD + k0, &Bs[(rsub + p * RPP) * BK + kb]);
    };

    auto compute = [&](int buf) {
        const unsigned short* As = sm + buf * TILE;
        const unsigned short* Bs = As + BM * BK;
        #pragma unroll
        for (int ks = 0; ks < BK / 32; ++ks) {
            bf16x8 a[AM], b[AN];
            #pragma unroll
            for (int mi = 0; mi < AM; ++mi) {
                const int ar = wr * WTM + mi * 16 + (lane & 15);
                const int cg = ks * 4 + (lane >> 4);
                a[mi] = *(const bf16x8*)&As[ar * BK + ((cg ^ (ar & 7)) * 8)];
            }
            #pragma unroll
            for (int ni = 0; ni < AN; ++ni) {
                const int br = wc * WTN + ni * 16 + (lane & 15);
                const int cg = ks * 4 + (lane >> 4);
                b[ni] = *(const bf16x8*)&Bs[br * BK + ((cg ^ (br & 7)) * 8)];
            }
            #pragma unroll
            for (int mi = 0; mi < AM; ++mi)
                #pragma unroll
                for (int ni = 0; ni < AN; ++ni)
                    acc[mi][ni] = __builtin_amdgcn_mfma_f32_16x16x32_bf16(
                        a[mi], b[ni], acc[mi][ni], 0, 0, 0);
        }
    };

    // prologue: 2 tiles in flight
    stage(0, 0);
    stage(1, BK);

    for (int it = 0; it < NIT; ++it) {
        __builtin_amdgcn_s_barrier();            // all waves retired compute(it-1)
        if (it + 2 < NIT) {
            stage((it + 2) % 3, (it + 2) * BK);  // overwrite target retired 1 iter ago
            wait_vmcnt<2 * L>();                 // my tile-it loads have landed
        } else if (it + 1 < NIT) {
            wait_vmcnt<L>();
        } else {
            wait_vmcnt<0>();
        }
        __builtin_amdgcn_s_barrier();            // everyone's tile-it in LDS
        compute(it % 3);
    }

    // C/D layout (m89/m91): col = lane&15, row = (lane>>4)*4 + reg.
    const int crow0 = bm * BM + wr * WTM + (lane >> 4) * 4;
    const int ccol0 = bn * BN + wc * WTN + (lane & 15);
    #pragma unroll
    for (int mi = 0; mi < AM; ++mi) {
        #pragma unroll
        for (int ni = 0; ni < AN; ++ni) {
            const int col = ccol0 + ni * 16;
            float bv = 0.f;
            if constexpr (BIAS) bv = bias[col];
            #pragma unroll
            for (int i = 0; i < 4; ++i) {
                const int row = crow0 + mi * 16 + i;
                float val = acc[mi][ni][i] + bv;
                if constexpr (std::is_same<OUT_T, float>::value)
                    C[(size_t)row * ND + col] = val;
                else
                    C[(size_t)row * ND + col] = f2bf(val);
            }
        }
    }
}

// ---------------- K1: weight prep ----------------
// blocks [0,256):   WvT[e,k] = bf16(Wqkv[vrow(k), e])  (16x16 tiles of 64x64)
// blocks [256,768): Wo -> bf16
// blocks [768,784): c[i] = bo[i] + sum_k Wo[i,k]*bqkv[vrow(k)]
__global__ __launch_bounds__(256) void prep_w(
    const float* __restrict__ Wqkv, const float* __restrict__ bqkv,
    const float* __restrict__ Wo, const float* __restrict__ bo,
    unsigned short* __restrict__ WvT, unsigned short* __restrict__ wo_bf,
    float* __restrict__ c)
{
    const int blk = blockIdx.x;
    const int t = threadIdx.x;
    if (blk < 256) {                        // ---- build WvT ----
        __shared__ unsigned short tile[64][65];
        const int eBase = (blk & 15) * 64, kBase = (blk >> 4) * 64;
        const int tx = t & 63, ty = t >> 6;
        #pragma unroll
        for (int r = ty; r < 64; r += 4) {
            int k = kBase + r;
            int j = ((k >> 6) * 192) + 128 + (k & 63);   // vrow(k)
            tile[r][tx] = f2bf(Wqkv[(size_t)j * EDIM + eBase + tx]);
        }
        __syncthreads();
        #pragma unroll
        for (int r = ty; r < 64; r += 4)
            WvT[(size_t)(eBase + r) * EDIM + kBase + tx] = tile[tx][r];
    } else if (blk < 768) {                 // ---- cast Wo ----
        cast8(Wo, wo_bf, (blk - 256) * 256 + t);
    } else {                                // ---- fused bias c ----
        const int b = blk - 768;            // 0..15
        const int wave = t >> 6, lane = t & 63;
        for (int r = 0; r < 16; ++r) {
            int row = b * 64 + wave * 16 + r;
            float s = 0.f;
            #pragma unroll
            for (int kk = 0; kk < 16; ++kk) {
                int k = kk * 64 + lane;
                int j = kk * 192 + 128 + lane;   // vrow(k)
                s += Wo[(size_t)row * EDIM + k] * bqkv[j];
            }
            #pragma unroll
            for (int off = 32; off > 0; off >>= 1) s += __shfl_down(s, off);
            if (lane == 0) c[row] = s + bo[row];
        }
    }
}

// ---------------- K2: gemm1 (M = Wo @ Wv_sub) co-dispatched with cast_x ----------------
// blocks [0,256):    M GEMM, 64x64 tiles (one block per CU), 3-buf counted-vmcnt
// blocks [256,2304): x -> bf16 (4M elems, 2048 elems/block)
__global__ __launch_bounds__(256, 2) void gemm1_castx(
    const unsigned short* __restrict__ wo_bf, const unsigned short* __restrict__ wvt,
    unsigned short* __restrict__ m_bf,
    const float* __restrict__ x, unsigned short* __restrict__ x_bf)
{
    __shared__ unsigned short smem[3 * (64 + 64) * 64];   // 48 KB
    const int blk = blockIdx.x;
    if (blk < 256) {
        gemm_bt_body<false, unsigned short, EDIM, EDIM, EDIM, 64, 64, 64, 2, 2>(
            wo_bf, wvt, m_bf, nullptr, blk, smem);
    } else {
        cast8(x, x_bf, (blk - 256) * 256 + threadIdx.x);
    }
}

// ---------------- K3: out = x @ M^T + c ----------------
// 128x64 tiles, BK=64, 3-buffer counted-vmcnt (vmcnt(12) steady state),
// 72 KB LDS -> 2 blocks/CU co-residency. T2 swizzle on LDS reads.
__global__ __launch_bounds__(256, 2) void gemm2(
    const unsigned short* __restrict__ x_bf, const unsigned short* __restrict__ m_bf,
    float* __restrict__ out, const float* __restrict__ cvec)
{
    __shared__ unsigned short smem[3 * (128 + 64) * 64];  // 72 KB
    gemm_bt_body<true, float, MROWS, EDIM, EDIM, 128, 64, 64, 2, 2>(
        x_bf, m_bf, out, cvec, blockIdx.x, smem);
}

extern "C" void kernel_launch(void* const* d_in, const int* in_sizes, int n_in,
                              void* d_out, int out_size, void* d_ws, size_t ws_size,
                              hipStream_t stream) {
    const float* x    = (const float*)d_in[0];   // (2,2048,1024)
    const float* Wqkv = (const float*)d_in[1];   // (3072,1024)
    const float* bqkv = (const float*)d_in[2];   // (3072,)
    const float* Wo   = (const float*)d_in[3];   // (1024,1024)
    const float* bo   = (const float*)d_in[4];   // (1024,)
    float* out = (float*)d_out;                  // (2,2048,1024) f32

    char* ws = (char*)d_ws;
    unsigned short* x_bf  = (unsigned short*)(ws);                       // 8 MB
    unsigned short* wvt   = (unsigned short*)(ws + 8u  * 1024 * 1024);   // 2 MB
    unsigned short* wo_bf = (unsigned short*)(ws + 10u * 1024 * 1024);   // 2 MB
    unsigned short* m_bf  = (unsigned short*)(ws + 12u * 1024 * 1024);   // 2 MB
    float*          cvec  = (float*)(ws + 14u * 1024 * 1024);            // 4 KB

    // K1: weight prep (WvT gather/transpose, Wo cast, fused bias c)
    prep_w<<<784, 256, 0, stream>>>(Wqkv, bqkv, Wo, bo, wvt, wo_bf, cvec);
    // K2: M = Wo @ Wv_sub (256 blocks, counted-vmcnt)  ||  x -> bf16 (2048 blocks)
    gemm1_castx<<<2304, 256, 0, stream>>>(wo_bf, wvt, m_bf, x, x_bf);
    // K3: out = x @ M^T + c (3-buffer counted-vmcnt + T2 swizzle)
    gemm2<<<512, 256, 0, stream>>>(x_bf, m_bf, out, cvec);
}

// Round 9
// 41.252 us; speedup vs baseline: 6.9147x; 1.0664x over previous
//
#include <hip/hip_runtime.h>
#include <hip/hip_bf16.h>
#include <type_traits>

// out = x @ M^T + c, with M = Wo @ Wv_sub (softmax row-sum == 1 collapses attn to v).
#define MROWS 4096   // B*S
#define EDIM  1024

typedef __attribute__((ext_vector_type(8))) __bf16 bf16x8;
typedef __attribute__((ext_vector_type(4))) float f32x4;
typedef __attribute__((ext_vector_type(8))) unsigned short ushort8;

__device__ __forceinline__ unsigned short f2bf(float f) {
    unsigned u = __builtin_bit_cast(unsigned, f);
    u += 0x7FFFu + ((u >> 16) & 1u);   // round-to-nearest-even
    return (unsigned short)(u >> 16);
}

__device__ __forceinline__ void async_load16(const void* g, void* l) {
    __builtin_amdgcn_global_load_lds(
        (const __attribute__((address_space(1))) void*)g,
        (__attribute__((address_space(3))) void*)l, 16, 0, 0);
}

template<int N> __device__ __forceinline__ void wait_vmcnt() {
    if constexpr (N == 0)       asm volatile("s_waitcnt vmcnt(0)" ::: "memory");
    else if constexpr (N == 4)  asm volatile("s_waitcnt vmcnt(4)" ::: "memory");
    else if constexpr (N == 6)  asm volatile("s_waitcnt vmcnt(6)" ::: "memory");
    else if constexpr (N == 8)  asm volatile("s_waitcnt vmcnt(8)" ::: "memory");
    else if constexpr (N == 12) asm volatile("s_waitcnt vmcnt(12)" ::: "memory");
    else static_assert(N < 0, "unsupported vmcnt literal");
}

// cast 8 consecutive f32 -> bf16 at flat ushort8 index i
__device__ __forceinline__ void cast8(const float* __restrict__ in,
                                      unsigned short* __restrict__ out, int i) {
    const float4* p = (const float4*)in + (size_t)i * 2;
    float4 a = p[0], b = p[1];
    ushort8 r;
    r[0] = f2bf(a.x); r[1] = f2bf(a.y); r[2] = f2bf(a.z); r[3] = f2bf(a.w);
    r[4] = f2bf(b.x); r[5] = f2bf(b.y); r[6] = f2bf(b.z); r[7] = f2bf(b.w);
    *((ushort8*)out + i) = r;
}

// ---------------- NBUF-buffer counted-vmcnt + T2-swizzled bf16 MFMA GEMM -------
// C[m,n] = sum_k A[m,k]*B[n,k] (+bias[n]). BMxBN tile, BK=64, NWM x NWN waves.
// T3+T4: NBUF-1 tiles in flight, raw s_barrier, counted vmcnt (never 0 in
// steady state). Stage of buf[(t+NBUF-1)%NBUF] issued only after the barrier
// proving compute(t-1) (that buffer's last reader) retired -> race-free.
// T2 (rule #21): global_load_lds writes LDS LINEARLY, so the bank-conflict
// swizzle is inverse-permuted GLOBAL SOURCE (kb ^ (row&7)*8) + same XOR on the
// ds_read address -> 16 fragment rows spread over all 32 banks.
// XCD-aware bijective swizzle: bm fastest within an XCD chunk (B panel L2-reuse).
// sm must hold NBUF*(BM+BN)*BK ushorts.
template<bool BIAS, typename OUT_T, int MD, int ND, int KD,
         int BM, int BN, int BK, int NWM, int NWN, int NBUF>
__device__ __forceinline__ void gemm_bt_body(
    const unsigned short* __restrict__ A, const unsigned short* __restrict__ B,
    OUT_T* __restrict__ C, const float* __restrict__ bias, int id,
    unsigned short* sm)
{
    constexpr int THREADS = NWM * NWN * 64;
    constexpr int NBM = MD / BM, NBN = ND / BN, NWG = NBM * NBN;
    constexpr int CPX = NWG / 8;
    constexpr int WTM = BM / NWM, WTN = BN / NWN;
    constexpr int AM = WTM / 16, AN = WTN / 16;
    constexpr int CHUNKS = BK / 8;        // 16B chunks per LDS row
    constexpr int RPP = THREADS / CHUNKS; // staging rows per pass
    constexpr int TILE = (BM + BN) * BK;  // ushorts per buffer
    constexpr int L = BM / RPP + BN / RPP;   // async loads per thread per stage
    constexpr int NIT = KD / BK;
    constexpr int AHEAD = NBUF - 1;
    static_assert(RPP % 8 == 0, "row-phase must be p-invariant for source swizzle");
    static_assert(CHUNKS == 8, "XOR swizzle assumes 8 chunks per row");

    const int t = threadIdx.x;
    const int swz = (id & 7) * CPX + (id >> 3);
    const int bm = swz % NBM, bn = swz / NBM;

    const int lane = t & 63, wave = t >> 6;
    const int wr = wave / NWN, wc = wave % NWN;

    const int rsub = t / CHUNKS;          // 0..RPP-1
    const int kb   = (t % CHUNKS) * 8;    // bf16-elem offset within BK (LDS dest)
    const int kbs  = kb ^ ((rsub & 7) * 8);  // inverse-swizzled global source

    const unsigned short* Ag = A + (size_t)(bm * BM + rsub) * KD + kbs;
    const unsigned short* Bg = B + (size_t)(bn * BN + rsub) * KD + kbs;

    f32x4 acc[AM][AN] = {};

    auto stage = [&](int buf, int k0) {
        unsigned short* As = sm + buf * TILE;
        unsigned short* Bs = As + BM * BK;
        #pragma unroll
        for (int p = 0; p < BM / RPP; ++p)
            async_load16(Ag + (size_t)(p * RPP) * KD + k0, &As[(rsub + p * RPP) * BK + kb]);
        #pragma unroll
        for (int p = 0; p < BN / RPP; ++p)
            async_load16(Bg + (size_t)(p * RPP) * KD + k0, &Bs[(rsub + p * RPP) * BK + kb]);
    };

    auto compute = [&](int buf) {
        const unsigned short* As = sm + buf * TILE;
        const unsigned short* Bs = As + BM * BK;
        #pragma unroll
        for (int ks = 0; ks < BK / 32; ++ks) {
            bf16x8 a[AM], b[AN];
            #pragma unroll
            for (int mi = 0; mi < AM; ++mi) {
                const int ar = wr * WTM + mi * 16 + (lane & 15);
                const int cg = ks * 4 + (lane >> 4);
                a[mi] = *(const bf16x8*)&As[ar * BK + ((cg ^ (ar & 7)) * 8)];
            }
            #pragma unroll
            for (int ni = 0; ni < AN; ++ni) {
                const int br = wc * WTN + ni * 16 + (lane & 15);
                const int cg = ks * 4 + (lane >> 4);
                b[ni] = *(const bf16x8*)&Bs[br * BK + ((cg ^ (br & 7)) * 8)];
            }
            #pragma unroll
            for (int mi = 0; mi < AM; ++mi)
                #pragma unroll
                for (int ni = 0; ni < AN; ++ni)
                    acc[mi][ni] = __builtin_amdgcn_mfma_f32_16x16x32_bf16(
                        a[mi], b[ni], acc[mi][ni], 0, 0, 0);
        }
    };

    // prologue: AHEAD tiles in flight
    #pragma unroll
    for (int p = 0; p < AHEAD; ++p) stage(p, p * BK);

    for (int it = 0; it < NIT; ++it) {
        __builtin_amdgcn_s_barrier();            // all waves retired compute(it-1)
        if (it + AHEAD < NIT) {
            stage((it + AHEAD) % NBUF, (it + AHEAD) * BK);
            wait_vmcnt<AHEAD * L>();             // my tile-it loads have landed
        } else if (it + 1 < NIT) {               // tail: fewer stages in flight
            wait_vmcnt<L>();                     // (NBUF<=3 -> at most 1 extra)
        } else {
            wait_vmcnt<0>();
        }
        __builtin_amdgcn_s_barrier();            // everyone's tile-it in LDS
        compute(it % NBUF);
    }

    // C/D layout (m89/m91): col = lane&15, row = (lane>>4)*4 + reg.
    const int crow0 = bm * BM + wr * WTM + (lane >> 4) * 4;
    const int ccol0 = bn * BN + wc * WTN + (lane & 15);
    #pragma unroll
    for (int mi = 0; mi < AM; ++mi) {
        #pragma unroll
        for (int ni = 0; ni < AN; ++ni) {
            const int col = ccol0 + ni * 16;
            float bv = 0.f;
            if constexpr (BIAS) bv = bias[col];
            #pragma unroll
            for (int i = 0; i < 4; ++i) {
                const int row = crow0 + mi * 16 + i;
                float val = acc[mi][ni][i] + bv;
                if constexpr (std::is_same<OUT_T, float>::value)
                    C[(size_t)row * ND + col] = val;
                else
                    C[(size_t)row * ND + col] = f2bf(val);
            }
        }
    }
}

// ---------------- K1: weight prep ----------------
// blocks [0,256):   WvT[e,k] = bf16(Wqkv[vrow(k), e])  (16x16 tiles of 64x64)
// blocks [256,768): Wo -> bf16
// blocks [768,784): c[i] = bo[i] + sum_k Wo[i,k]*bqkv[vrow(k)]
__global__ __launch_bounds__(256) void prep_w(
    const float* __restrict__ Wqkv, const float* __restrict__ bqkv,
    const float* __restrict__ Wo, const float* __restrict__ bo,
    unsigned short* __restrict__ WvT, unsigned short* __restrict__ wo_bf,
    float* __restrict__ c)
{
    const int blk = blockIdx.x;
    const int t = threadIdx.x;
    if (blk < 256) {                        // ---- build WvT ----
        __shared__ unsigned short tile[64][65];
        const int eBase = (blk & 15) * 64, kBase = (blk >> 4) * 64;
        const int tx = t & 63, ty = t >> 6;
        #pragma unroll
        for (int r = ty; r < 64; r += 4) {
            int k = kBase + r;
            int j = ((k >> 6) * 192) + 128 + (k & 63);   // vrow(k)
            tile[r][tx] = f2bf(Wqkv[(size_t)j * EDIM + eBase + tx]);
        }
        __syncthreads();
        #pragma unroll
        for (int r = ty; r < 64; r += 4)
            WvT[(size_t)(eBase + r) * EDIM + kBase + tx] = tile[tx][r];
    } else if (blk < 768) {                 // ---- cast Wo ----
        cast8(Wo, wo_bf, (blk - 256) * 256 + t);
    } else {                                // ---- fused bias c ----
        const int b = blk - 768;            // 0..15
        const int wave = t >> 6, lane = t & 63;
        for (int r = 0; r < 16; ++r) {
            int row = b * 64 + wave * 16 + r;
            float s = 0.f;
            #pragma unroll
            for (int kk = 0; kk < 16; ++kk) {
                int k = kk * 64 + lane;
                int j = kk * 192 + 128 + lane;   // vrow(k)
                s += Wo[(size_t)row * EDIM + k] * bqkv[j];
            }
            #pragma unroll
            for (int off = 32; off > 0; off >>= 1) s += __shfl_down(s, off);
            if (lane == 0) c[row] = s + bo[row];
        }
    }
}

// ---------------- K2: gemm1 (M = Wo @ Wv_sub) co-dispatched with cast_x ----------------
// blocks [0,256):    M GEMM, 64x64 tiles (one block per CU), 3-buf counted-vmcnt
// blocks [256,2304): x -> bf16 (4M elems, 2048 elems/block)
__global__ __launch_bounds__(256, 2) void gemm1_castx(
    const unsigned short* __restrict__ wo_bf, const unsigned short* __restrict__ wvt,
    unsigned short* __restrict__ m_bf,
    const float* __restrict__ x, unsigned short* __restrict__ x_bf)
{
    __shared__ unsigned short smem[3 * (64 + 64) * 64];   // 48 KB
    const int blk = blockIdx.x;
    if (blk < 256) {
        gemm_bt_body<false, unsigned short, EDIM, EDIM, EDIM, 64, 64, 64, 2, 2, 3>(
            wo_bf, wvt, m_bf, nullptr, blk, smem);
    } else {
        cast8(x, x_bf, (blk - 256) * 256 + threadIdx.x);
    }
}

// ---------------- K3: out = x @ M^T + c ----------------
// 128x128 tiles (staging refetch 192->128 MB vs 128x64), 8 waves (2x4 grid,
// acc[4][2], 2 waves/SIMD TLP), 2-buffer counted-vmcnt (steady vmcnt(4)),
// 64 KB LDS, grid 256. T2 swizzle on LDS reads.
__global__ __launch_bounds__(512, 2) void gemm2(
    const unsigned short* __restrict__ x_bf, const unsigned short* __restrict__ m_bf,
    float* __restrict__ out, const float* __restrict__ cvec)
{
    __shared__ unsigned short smem[2 * (128 + 128) * 64];  // 64 KB
    gemm_bt_body<true, float, MROWS, EDIM, EDIM, 128, 128, 64, 2, 4, 2>(
        x_bf, m_bf, out, cvec, blockIdx.x, smem);
}

extern "C" void kernel_launch(void* const* d_in, const int* in_sizes, int n_in,
                              void* d_out, int out_size, void* d_ws, size_t ws_size,
                              hipStream_t stream) {
    const float* x    = (const float*)d_in[0];   // (2,2048,1024)
    const float* Wqkv = (const float*)d_in[1];   // (3072,1024)
    const float* bqkv = (const float*)d_in[2];   // (3072,)
    const float* Wo   = (const float*)d_in[3];   // (1024,1024)
    const float* bo   = (const float*)d_in[4];   // (1024,)
    float* out = (float*)d_out;                  // (2,2048,1024) f32

    char* ws = (char*)d_ws;
    unsigned short* x_bf  = (unsigned short*)(ws);                       // 8 MB
    unsigned short* wvt   = (unsigned short*)(ws + 8u  * 1024 * 1024);   // 2 MB
    unsigned short* wo_bf = (unsigned short*)(ws + 10u * 1024 * 1024);   // 2 MB
    unsigned short* m_bf  = (unsigned short*)(ws + 12u * 1024 * 1024);   // 2 MB
    float*          cvec  = (float*)(ws + 14u * 1024 * 1024);            // 4 KB

    // K1: weight prep (WvT gather/transpose, Wo cast, fused bias c)
    prep_w<<<784, 256, 0, stream>>>(Wqkv, bqkv, Wo, bo, wvt, wo_bf, cvec);
    // K2: M = Wo @ Wv_sub (256 blocks, counted-vmcnt)  ||  x -> bf16 (2048 blocks)
    gemm1_castx<<<2304, 256, 0, stream>>>(wo_bf, wvt, m_bf, x, x_bf);
    // K3: out = x @ M^T + c (128x128, 8 waves, 2-buf counted-vmcnt + T2 swizzle)
    gemm2<<<256, 512, 0, stream>>>(x_bf, m_bf, out, cvec);
}